// Round 6
// baseline (383.983 us; speedup 1.0000x reference)
//
#include <hip/hip_runtime.h>

#define SN 6400      // H*W
#define CN 256       // channels (= GEMM K)
#define NBATCH 2
#define NFT 100      // row-tiles of 64 (SN/64)
#define NCHUNK 5     // col chunks per pass
#define TPC 10       // 128-row B-tiles per chunk (50 total)

typedef _Float16 f16;
typedef f16 f16x8 __attribute__((ext_vector_type(8)));
typedef float f32x4 __attribute__((ext_vector_type(4)));

// ---------------- prep kernels ----------------

__global__ __launch_bounds__(256) void k_zero(float* __restrict__ a,
                                              float* __restrict__ b) {
    int i = blockIdx.x * 256 + threadIdx.x;
    a[i] = 0.f; b[i] = 0.f;
}

__global__ __launch_bounds__(256) void k_meanT(const float* __restrict__ T,
                                               float* __restrict__ meanT) {
    int c = blockIdx.x, t = threadIdx.x;
    const float* p0 = T + (size_t)c * SN;
    const float* p1 = T + (size_t)(CN + c) * SN;
    float s = 0.f;
    for (int i = t; i < SN; i += 256) s += p0[i] + p1[i];
    #pragma unroll
    for (int d = 1; d < 64; d <<= 1) s += __shfl_xor(s, d, 64);
    __shared__ float sb[4];
    if ((t & 63) == 0) sb[t >> 6] = s;
    __syncthreads();
    if (t == 0) meanT[c] = (sb[0] + sb[1] + sb[2] + sb[3]) * (1.0f / 12800.0f);
}

// transpose [n,c,s] -> [n,s,c], center, cast fp16, accumulate sum-of-squares
// per (n,s) via atomics (norm applied later in the GEMM epilogue).
__global__ __launch_bounds__(256) void k_xpose(const float* __restrict__ X,
                                               const float* __restrict__ meanT,
                                               f16* __restrict__ out,
                                               float* __restrict__ ssq) {
    int n = blockIdx.z, c0 = blockIdx.y * 32, s0 = blockIdx.x * 64;
    __shared__ float tile[32][65];
    int tx = threadIdx.x & 63, ty = threadIdx.x >> 6;
    const float* Xb = X + ((size_t)n * CN + c0) * SN + s0;
    #pragma unroll
    for (int cy = ty; cy < 32; cy += 4)
        tile[cy][tx] = Xb[(size_t)cy * SN + tx] - meanT[c0 + cy];
    __syncthreads();
    int cc = threadIdx.x & 31, sy = threadIdx.x >> 5;
    f16* ob = out + ((size_t)n * SN + s0) * CN + c0;
    float* sq = ssq + (size_t)n * SN + s0;
    #pragma unroll
    for (int sr = sy; sr < 64; sr += 8) {
        f16 hv = (f16)tile[cc][sr];
        ob[(size_t)sr * CN + cc] = hv;
        float vf = (float)hv;
        float v2 = vf * vf;
        #pragma unroll
        for (int d = 1; d < 32; d <<= 1) v2 += __shfl_xor(v2, d, 64);
        if (cc == 0) atomicAdd(&sq[sr], v2);
    }
}

// in-place ssq -> rsqrt (both arrays)
__global__ __launch_bounds__(256) void k_finv(float* __restrict__ a,
                                              float* __restrict__ b) {
    int i = blockIdx.x * 256 + threadIdx.x;
    a[i] = rsqrtf(a[i]);
    b[i] = rsqrtf(b[i]);
}

// ---------------- flat GEMM passes (no LDS in K-loop) ----------------
// Block: 64 A-rows (fixed, fragments in 128 VGPRs) x 128 B-rows per loop tile.
// 4 waves side-by-side over cols (wave wv covers B rows wv*32..wv*32+31).
// B fragments load directly global->VGPR (L2/L3-resident, shared across the
// blocks of one chunk). Normalization folded into the epilogue:
//   cos(i,j) = acc * sRow[i] * sCol[j].
// PASS 0: per-row max of cos
// PASS 1: per-row sum of exp2(a0 + a1*acc*csc)   (a1 includes rsc, g)
// PASS 2 (A=T): per-T-row max over cols i of (alpha_i - g_i*raw)
template <int PASS>
__global__ __launch_bounds__(256, 2) void k_gemm(const f16* __restrict__ A,
                                                 const f16* __restrict__ B,
                                                 const float* __restrict__ sRow,
                                                 const float* __restrict__ sCol,
                                                 const float* __restrict__ grow,
                                                 const float* __restrict__ alpha,
                                                 float* __restrict__ outP) {
    const int n = blockIdx.z, chunk = blockIdx.y, ft = blockIdx.x;
    const int tid = threadIdx.x, lane = tid & 63, wv = tid >> 6;
    const int quad = lane >> 4, lrow = lane & 15;

    const f16* An = A + (size_t)n * SN * CN;
    const f16* Bn = B + (size_t)n * SN * CN;

    // ---- prologue: A fragments (64 rows x K=256) -> registers ----
    f16x8 af[4][8];
    #pragma unroll
    for (int mt = 0; mt < 4; ++mt) {
        const f16* ap = An + (size_t)(ft * 64 + mt * 16 + lrow) * CN + quad * 8;
        #pragma unroll
        for (int ks = 0; ks < 8; ++ks)
            af[mt][ks] = *(const f16x8*)(ap + ks * 32);
    }

    // row-fixed coefficients (C/D row = mt*16 + quad*4 + v)
    float rsc[4][4], a0c[4][4], a1c[4][4];
    #pragma unroll
    for (int mt = 0; mt < 4; ++mt)
        #pragma unroll
        for (int v = 0; v < 4; ++v) {
            int r = ft * 64 + mt * 16 + quad * 4 + v;
            float rs = sRow[(size_t)n * SN + r];
            if constexpr (PASS == 1) {
                float gg = grow[(size_t)n * SN + r];
                a1c[mt][v] = 0.5f * gg * 1.44269504089f * rs;
                a0c[mt][v] = (10.f - 0.5f * gg) * 1.44269504089f;
            } else {
                rsc[mt][v] = rs;
            }
        }

    float runRow[4][4];
    #pragma unroll
    for (int mt = 0; mt < 4; ++mt)
        #pragma unroll
        for (int v = 0; v < 4; ++v) runRow[mt][v] = (PASS == 1) ? 0.f : -3.0e38f;

    #pragma unroll 1
    for (int t = 0; t < TPC; ++t) {
        const int bt = chunk * TPC + t;
        const f16* Bt = Bn + ((size_t)bt * 128 + wv * 32 + lrow) * CN + quad * 8;

        float csc[2], gl[2], al[2];
        #pragma unroll
        for (int nt = 0; nt < 2; ++nt) {
            int j = bt * 128 + wv * 32 + nt * 16 + lrow;
            csc[nt] = sCol[(size_t)n * SN + j];
            if constexpr (PASS == 2) {
                gl[nt] = grow[(size_t)n * SN + j];
                al[nt] = alpha[(size_t)n * SN + j];
            }
        }

        f32x4 acc[4][2];
        #pragma unroll
        for (int mt = 0; mt < 4; ++mt)
            #pragma unroll
            for (int nt = 0; nt < 2; ++nt) acc[mt][nt] = (f32x4){0.f, 0.f, 0.f, 0.f};

        #pragma unroll
        for (int ks = 0; ks < 8; ++ks) {
            f16x8 b0 = *(const f16x8*)(Bt + ks * 32);
            f16x8 b1 = *(const f16x8*)(Bt + (size_t)16 * CN + ks * 32);
            #pragma unroll
            for (int mt = 0; mt < 4; ++mt)
                acc[mt][0] = __builtin_amdgcn_mfma_f32_16x16x32_f16(
                    af[mt][ks], b0, acc[mt][0], 0, 0, 0);
            #pragma unroll
            for (int mt = 0; mt < 4; ++mt)
                acc[mt][1] = __builtin_amdgcn_mfma_f32_16x16x32_f16(
                    af[mt][ks], b1, acc[mt][1], 0, 0, 0);
        }

        // ---- per-tile epilogue (registers only, no barrier) ----
        if constexpr (PASS == 0) {
            #pragma unroll
            for (int mt = 0; mt < 4; ++mt)
                #pragma unroll
                for (int v = 0; v < 4; ++v) {
                    float m = fmaxf(acc[mt][0][v] * csc[0], acc[mt][1][v] * csc[1]);
                    runRow[mt][v] = fmaxf(runRow[mt][v], m);
                }
        } else if constexpr (PASS == 1) {
            #pragma unroll
            for (int mt = 0; mt < 4; ++mt)
                #pragma unroll
                for (int v = 0; v < 4; ++v) {
                    float s = runRow[mt][v];
                    #pragma unroll
                    for (int nt = 0; nt < 2; ++nt) {
                        float tt = acc[mt][nt][v] * csc[nt];
                        float arg = fminf(14.4269504089f,
                                          fmaf(tt, a1c[mt][v], a0c[mt][v]));
                        s += exp2f(arg);
                    }
                    runRow[mt][v] = s;
                }
        } else {
            float m5[2] = {-0.5f * csc[0], -0.5f * csc[1]};
            #pragma unroll
            for (int mt = 0; mt < 4; ++mt)
                #pragma unroll
                for (int v = 0; v < 4; ++v) {
                    #pragma unroll
                    for (int nt = 0; nt < 2; ++nt) {
                        float tt = acc[mt][nt][v] * rsc[mt][v];
                        float raw = fmaxf(0.f, fmaf(tt, m5[nt], 0.5f));
                        float lc = fmaf(-gl[nt], raw, al[nt]);
                        runRow[mt][v] = fmaxf(runRow[mt][v], lc);
                    }
                }
        }
    }

    // ---- reduction: over lrow (in-wave), then across 4 waves via tiny LDS ----
    __shared__ float red[4][64];
    #pragma unroll
    for (int mt = 0; mt < 4; ++mt)
        #pragma unroll
        for (int v = 0; v < 4; ++v) {
            float val = runRow[mt][v];
            if constexpr (PASS == 0) val *= rsc[mt][v];   // apply row norm once
            #pragma unroll
            for (int d = 1; d < 16; d <<= 1) {
                float o = __shfl_xor(val, d, 64);
                val = (PASS == 1) ? (val + o) : fmaxf(val, o);
            }
            if (lrow == 0) red[wv][mt * 16 + quad * 4 + v] = val;
        }
    __syncthreads();
    if (tid < 64) {
        float a = red[0][tid], b = red[1][tid], c = red[2][tid], d = red[3][tid];
        float r = (PASS == 1) ? (a + b + c + d)
                              : fmaxf(fmaxf(a, b), fmaxf(c, d));
        outP[(size_t)(n * NCHUNK + chunk) * SN + ft * 64 + tid] = r;
    }
}

// ---------------- small reduce kernels ----------------

__global__ __launch_bounds__(256) void r_g(const float* __restrict__ rowmaxP,
                                           float* __restrict__ grow) {
    int idx = blockIdx.x * 256 + threadIdx.x;
    int n = idx / SN, i = idx - n * SN;
    float m = -3.0e38f;
    for (int ch = 0; ch < NCHUNK; ++ch)
        m = fmaxf(m, rowmaxP[(size_t)(n * NCHUNK + ch) * SN + i]);
    float mr = fmaxf(0.f, (1.f - m) * 0.5f);
    grow[idx] = 10.f / (mr + 1e-5f);
}

__global__ __launch_bounds__(256) void r_alpha(const float* __restrict__ rowsumP,
                                               float* __restrict__ alpha) {
    int idx = blockIdx.x * 256 + threadIdx.x;
    int n = idx / SN, i = idx - n * SN;
    float s = 0.f;
    for (int ch = 0; ch < NCHUNK; ++ch)
        s += rowsumP[(size_t)(n * NCHUNK + ch) * SN + i];
    alpha[idx] = 10.f - logf(s);
}

__global__ __launch_bounds__(256) void r_colfin(const float* __restrict__ colmaxP,
                                                float* __restrict__ bsum) {
    int idx = blockIdx.x * 256 + threadIdx.x;
    int n = idx / SN, j = idx - n * SN;
    float m = -3.0e38f;
    for (int ch = 0; ch < NCHUNK; ++ch)
        m = fmaxf(m, colmaxP[(size_t)(n * NCHUNK + ch) * SN + j]);
    float v = expf(m);
    #pragma unroll
    for (int d = 1; d < 64; d <<= 1) v += __shfl_xor(v, d, 64);
    __shared__ float sb[4];
    if ((threadIdx.x & 63) == 0) sb[threadIdx.x >> 6] = v;
    __syncthreads();
    if (threadIdx.x == 0) bsum[blockIdx.x] = sb[0] + sb[1] + sb[2] + sb[3];
}

__global__ __launch_bounds__(64) void r_loss(const float* __restrict__ bsum,
                                             float* __restrict__ out) {
    int t = threadIdx.x;
    float v = (t < 50) ? bsum[t] : 0.f;
    float v0 = (t < 25) ? v : 0.f;
    float v1 = (t >= 25 && t < 50) ? v : 0.f;
    #pragma unroll
    for (int d = 1; d < 64; d <<= 1) {
        v0 += __shfl_xor(v0, d, 64);
        v1 += __shfl_xor(v1, d, 64);
    }
    if (t == 0) {
        float cs0 = v0 * (1.0f / SN), cs1 = v1 * (1.0f / SN);
        out[0] = -0.5f * (logf(cs0) + logf(cs1));
    }
}

// ---------------- launch ----------------

extern "C" void kernel_launch(void* const* d_in, const int* in_sizes, int n_in,
                              void* d_out, int out_size, void* d_ws, size_t ws_size,
                              hipStream_t stream) {
    const float* I = (const float*)d_in[0];
    const float* T = (const float*)d_in[1];
    float* out = (float*)d_out;

    float* wsf = (float*)d_ws;
    float* meanT = wsf;                        // 256
    float* ssqI  = meanT + 256;                // 12800 (becomes invNI)
    float* ssqT  = ssqI + 12800;               // 12800 (becomes invNT)
    float* grow  = ssqT + 12800;               // 12800
    float* alpha = grow + 12800;               // 12800
    float* rowmaxP = alpha + 12800;            // 64000
    float* rowsumP = rowmaxP + 64000;          // 64000
    float* colmaxP = rowsumP + 64000;          // 64000
    float* bsum = colmaxP + 64000;             // 64
    f16* Ah = (f16*)(bsum + 64);               // centered I, [n,s,c] fp16
    f16* Bh = Ah + (size_t)NBATCH * SN * CN;   // centered T; total ws ~14.1 MB

    k_zero<<<50, 256, 0, stream>>>(ssqI, ssqT);
    k_meanT<<<256, 256, 0, stream>>>(T, meanT);
    k_xpose<<<dim3(100, 8, 2), 256, 0, stream>>>(I, meanT, Ah, ssqI);
    k_xpose<<<dim3(100, 8, 2), 256, 0, stream>>>(T, meanT, Bh, ssqT);
    k_finv<<<50, 256, 0, stream>>>(ssqI, ssqT);

    dim3 gg(NFT, NCHUNK, NBATCH);
    k_gemm<0><<<gg, 256, 0, stream>>>(Ah, Bh, ssqI, ssqT, nullptr, nullptr, rowmaxP);
    r_g<<<50, 256, 0, stream>>>(rowmaxP, grow);
    k_gemm<1><<<gg, 256, 0, stream>>>(Ah, Bh, ssqI, ssqT, grow, nullptr, rowsumP);
    r_alpha<<<50, 256, 0, stream>>>(rowsumP, alpha);
    k_gemm<2><<<gg, 256, 0, stream>>>(Bh, Ah, ssqT, ssqI, grow, alpha, colmaxP);
    r_colfin<<<50, 256, 0, stream>>>(colmaxP, bsum);
    r_loss<<<1, 64, 0, stream>>>(bsum, out);
}